// Round 8
// baseline (133.443 us; speedup 1.0000x reference)
//
#include <hip/hip_runtime.h>
#include <stdint.h>

// ---------------------------------------------------------------------------
// MultiDilatelocalAttention (B=4, H=W=128, C=256, heads=8, K=3, dil={2,3})
//   1) qkv = x @ Wqkv^T            (bf16 MFMA GEMM, M=65536 N=768 K=256)
//   2) dilated 3x3 local attention per (pixel, combo) thread
//   3) out = xo @ Wproj^T + bproj  (bf16 MFMA GEMM, fp32 out)
// GEMM (R7): BK=32, 4 resident blocks/CU, counted-vmcnt depth-2 pipeline,
// T1 XCD-chunked N-major swizzle, T2 XOR swizzle, LDS-staged epilogue.
// attn R8: R5 structure, but tap loads made UNCONDITIONAL via address
// clamping (clamp hh,ww to [0,127]); zero-pad semantics applied to RESULTS
// (sc = ok ? s : 0; wv_eff = ok ? wv : 0). The R5/R7 version kept loads
// inside divergent branches -> compiler couldn't hoist -> 19 serialized L2
// round trips/thread (VALUBusy 34%, VGPR 44 = no prefetch depth). Clamped
// loads are always-valid, speculative-safe, and pipeline freely.
// ---------------------------------------------------------------------------

typedef __attribute__((ext_vector_type(8))) short bf16x8;
typedef __attribute__((ext_vector_type(4))) float f32x4;

__device__ __forceinline__ void unpack2(unsigned u, float& lo, float& hi) {
  union { unsigned u; float f; } a, b;
  a.u = u << 16;
  b.u = u & 0xffff0000u;
  lo = a.f; hi = b.f;
}
__device__ __forceinline__ unsigned short f2bf(float f) {
  union { float f; unsigned u; } x; x.f = f;
  unsigned r = x.u + 0x7fffu + ((x.u >> 16) & 1u);   // RNE
  return (unsigned short)(r >> 16);
}
__device__ __forceinline__ unsigned pk2bf(float a, float b) {
  return (unsigned)f2bf(a) | ((unsigned)f2bf(b) << 16);
}

// ------------------------------- fp32 -> bf16 ------------------------------
__global__ __launch_bounds__(256) void cvt_f32_to_bf16(
    const float* __restrict__ src, unsigned short* __restrict__ dst, int n) {
  int i = (blockIdx.x * 256 + threadIdx.x) * 8;
  if (i + 8 <= n) {
    const float4* s = (const float4*)(src + i);
    float4 a = s[0], b = s[1];
    uint4 o;
    o.x = pk2bf(a.x, a.y); o.y = pk2bf(a.z, a.w);
    o.z = pk2bf(b.x, b.y); o.w = pk2bf(b.z, b.w);
    *(uint4*)(dst + i) = o;
  } else {
    for (; i < n; ++i) dst[i] = f2bf(src[i]);
  }
}

// ------------------------- GEMM: C = A @ B^T (bf16) ------------------------
#define BARX()                                                \
  do {                                                        \
    asm volatile("s_waitcnt lgkmcnt(0)" ::: "memory");        \
    __builtin_amdgcn_s_barrier();                             \
    __builtin_amdgcn_sched_barrier(0);                        \
  } while (0)
#define WAITVM(n)                                             \
  do {                                                        \
    asm volatile("s_waitcnt vmcnt(" #n ")" ::: "memory");     \
    __builtin_amdgcn_sched_barrier(0);                        \
  } while (0)

template <int OUTF32>
__global__ __launch_bounds__(256) void gemm_bt(
    const unsigned short* __restrict__ A, const unsigned short* __restrict__ B,
    void* __restrict__ Cout, const float* __restrict__ bias,
    int N, int NT) {
  // K-loop: A0[0,4096) B0[4096,8192) A1[8192,12288) B1[12288,16384) ushorts,
  // each tile 128x32 bf16 = 8 KB. Epilogue reuses [0,17408) = 34816 B total.
  __shared__ __align__(16) unsigned short lds[17408];

  const int tid  = threadIdx.x;
  const int lane = tid & 63;
  const int wv   = tid >> 6;
  const int wr   = wv >> 1;   // wave row (0..1)
  const int wc   = wv & 1;    // wave col (0..1)

  // XCD-chunked bijective swizzle (gridDim.x % 8 == 0), N-major tile order.
  const int nwg = gridDim.x;
  const int q8  = nwg >> 3;
  const int nid = (blockIdx.x & 7) * q8 + (blockIdx.x >> 3);
  const int n0  = (nid % NT) * 128;
  const int m0  = (nid / NT) * 128;

  // staging (BK=32): per issue `it` (0..1), wave wv writes 1 KB linearly at
  // elem = it*2048 + wv*512 + l*8 -> row = it*64 + wv*16 + (l>>2), gran = l&3.
  // T2: lane fetches global granule (l&3)^key, key=(row>>1)&3=(l>>3)&3.
  const int stg_row = wv * 16 + (lane >> 2);
  const int stg_k   = ((lane & 3) ^ ((lane >> 3) & 3)) * 8;
  const unsigned short* Ag = A + (size_t)(m0 + stg_row) * 256 + stg_k;
  const unsigned short* Bg = B + (size_t)(n0 + stg_row) * 256 + stg_k;

  f32x4 acc[4][4];
#pragma unroll
  for (int i = 0; i < 4; ++i)
#pragma unroll
    for (int j = 0; j < 4; ++j) acc[i][j] = (f32x4){0.f, 0.f, 0.f, 0.f};

  const int a_r = lane & 15;   // row within 16x16 fragment (row&15)

#define STAGE(buf, kt)                                                         \
  do {                                                                         \
    const unsigned short* Asrc = Ag + (kt) * 32;                               \
    const unsigned short* Bsrc = Bg + (kt) * 32;                               \
    _Pragma("unroll")                                                          \
    for (int it = 0; it < 2; ++it) {                                           \
      __builtin_amdgcn_global_load_lds(                                        \
          (const __attribute__((address_space(1))) void*)(Asrc + (size_t)it * 64 * 256), \
          (__attribute__((address_space(3))) void*)&lds[(buf) * 8192 + it * 2048 + wv * 512], \
          16, 0, 0);                                                           \
      __builtin_amdgcn_global_load_lds(                                        \
          (const __attribute__((address_space(1))) void*)(Bsrc + (size_t)it * 64 * 256), \
          (__attribute__((address_space(3))) void*)&lds[(buf) * 8192 + 4096 + it * 2048 + wv * 512], \
          16, 0, 0);                                                           \
    }                                                                          \
  } while (0)

// read swizzle: nominal gran = lane>>4, key = (row>>1)&3 = (lane>>1)&3
// (all fragment row bases are multiples of 16, row = base + (lane&15)).
#define COMPUTE(buf)                                                           \
  do {                                                                         \
    const int gsw = (((lane >> 4) ^ ((lane >> 1) & 3))) * 8;                   \
    bf16x8 af[4], bfr[4];                                                      \
    _Pragma("unroll")                                                          \
    for (int mi = 0; mi < 4; ++mi)                                             \
      af[mi] = *(const bf16x8*)&lds[(buf) * 8192 + (wr * 64 + mi * 16 + a_r) * 32 + gsw]; \
    _Pragma("unroll")                                                          \
    for (int ni = 0; ni < 4; ++ni)                                             \
      bfr[ni] = *(const bf16x8*)&lds[(buf) * 8192 + 4096 + (wc * 64 + ni * 16 + a_r) * 32 + gsw]; \
    _Pragma("unroll")                                                          \
    for (int mi = 0; mi < 4; ++mi)                                             \
      _Pragma("unroll")                                                        \
      for (int ni = 0; ni < 4; ++ni)                                           \
        acc[mi][ni] = __builtin_amdgcn_mfma_f32_16x16x32_bf16(                 \
            af[mi], bfr[ni], acc[mi][ni], 0, 0, 0);                            \
  } while (0)

  // Depth-2 prefetch, 4 loads/wave per STAGE; counted vmcnt, never 0 until
  // the final tile. 8 K-tiles rotate buffers 0,1,0,1,...
  STAGE(0, 0);
  STAGE(1, 1);
  WAITVM(4);  BARX();
  COMPUTE(0);  BARX();
  STAGE(0, 2); WAITVM(4); BARX();
  COMPUTE(1);  BARX();
  STAGE(1, 3); WAITVM(4); BARX();
  COMPUTE(0);  BARX();
  STAGE(0, 4); WAITVM(4); BARX();
  COMPUTE(1);  BARX();
  STAGE(1, 5); WAITVM(4); BARX();
  COMPUTE(0);  BARX();
  STAGE(0, 6); WAITVM(4); BARX();
  COMPUTE(1);  BARX();
  STAGE(1, 7); WAITVM(4); BARX();
  COMPUTE(0);  BARX();
  WAITVM(0);   BARX();
  COMPUTE(1);  BARX();   // LDS about to be reused by epilogue

  // ------------------- LDS-staged coalesced epilogue -------------------
  const int cl = wc * 64 + a_r;              // local col base
  const int rl = wr * 64 + (lane >> 4) * 4;  // local row base
  if (!OUTF32) {
    // 128 rows x (128+8) bf16 = 17408 ushorts (16B-aligned rows, bank spread)
    unsigned short* eb = &lds[0];
#pragma unroll
    for (int ni = 0; ni < 4; ++ni)
#pragma unroll
      for (int mi = 0; mi < 4; ++mi)
#pragma unroll
        for (int r = 0; r < 4; ++r)
          eb[(rl + mi * 16 + r) * 136 + cl + ni * 16] = f2bf(acc[mi][ni][r]);
    BARX();   // lgkmcnt(0) drain inside: publishes ds_writes to all waves
    unsigned short* C = (unsigned short*)Cout;
#pragma unroll
    for (int p = 0; p < 8; ++p) {
      const int idx = p * 256 + tid;
      const int row = idx >> 4;
      const int seg = idx & 15;
      uint4 v = *(const uint4*)&eb[row * 136 + seg * 8];
      *(uint4*)&C[(size_t)(m0 + row) * N + n0 + seg * 8] = v;
    }
  } else {
    // f32: two 64-row halves of (128+4)-f32-stride rows (33792 B each)
    float* ef = (float*)&lds[0];
    float* C = (float*)Cout;
    float bv[4];
#pragma unroll
    for (int ni = 0; ni < 4; ++ni) bv[ni] = bias[n0 + wc * 64 + ni * 16 + a_r];
#pragma unroll
    for (int half = 0; half < 2; ++half) {
      if (wr == half) {
        const int rb = (lane >> 4) * 4;   // local row within the half
#pragma unroll
        for (int ni = 0; ni < 4; ++ni)
#pragma unroll
          for (int mi = 0; mi < 4; ++mi)
#pragma unroll
            for (int r = 0; r < 4; ++r)
              ef[(rb + mi * 16 + r) * 132 + wc * 64 + ni * 16 + a_r] =
                  acc[mi][ni][r] + bv[ni];
      }
      BARX();   // lgkmcnt(0) drain inside
#pragma unroll
      for (int p = 0; p < 8; ++p) {
        const int idx = p * 256 + tid;
        const int row = idx >> 5;
        const int seg = idx & 31;
        f32x4 v = *(const f32x4*)&ef[row * 132 + seg * 4];
        *(f32x4*)&C[(size_t)(m0 + half * 64 + row) * N + n0 + seg * 4] = v;
      }
      BARX();
    }
  }
#undef STAGE
#undef COMPUTE
}

// --------------------------- dilated local attention -----------------------
// qkv: [pixel][768] bf16, one thread per (pixel, combo=branch*4+head), 32 ch.
// R8: all tap loads unconditional (clamped addresses), zero-pad semantics via
// result predication -> compiler can pipeline the 9 independent tap loads.
__global__ __launch_bounds__(256) void attn_kernel(
    const unsigned short* __restrict__ qkv, unsigned short* __restrict__ xo) {
  const int nwg = gridDim.x;
  const int q8  = nwg >> 3;
  const int bid = (blockIdx.x & 7) * q8 + (blockIdx.x >> 3);
  const int gid   = bid * 256 + threadIdx.x;
  const int combo = gid & 7;
  const int pixel = gid >> 3;
  const int w = pixel & 127;
  const int h = (pixel >> 7) & 127;
  const int b = pixel >> 14;
  const int dil = (combo >> 2) ? 3 : 2;     // DILATIONS = (2, 3)
  const int choff = combo * 32;             // = branch*128 + head*32

  const unsigned short* qp = qkv + (size_t)pixel * 768 + choff;
  float q[32];
#pragma unroll
  for (int t = 0; t < 4; ++t) {
    uint4 u = *(const uint4*)(qp + t * 8);
    unpack2(u.x, q[t * 8 + 0], q[t * 8 + 1]);
    unpack2(u.y, q[t * 8 + 2], q[t * 8 + 3]);
    unpack2(u.z, q[t * 8 + 4], q[t * 8 + 5]);
    unpack2(u.w, q[t * 8 + 6], q[t * 8 + 7]);
  }

  // scores: zero-padded unfold => OOB taps have score exactly 0 (not -inf).
  // Loads are unconditional (clamped addr, always valid, finite data);
  // predication applied to the score result only.
  float sc[9];
#pragma unroll
  for (int i = 0; i < 3; ++i) {
#pragma unroll
    for (int j = 0; j < 3; ++j) {
      const int hh = h + (i - 1) * dil;
      const int ww = w + (j - 1) * dil;
      const bool ok = ((unsigned)hh < 128u) && ((unsigned)ww < 128u);
      const int hcl = min(max(hh, 0), 127);
      const int wcl = min(max(ww, 0), 127);
      const unsigned short* kp =
          qkv + (size_t)((((b << 7) | hcl) << 7) | wcl) * 768 + 256 + choff;
      float s = 0.f;
#pragma unroll
      for (int t = 0; t < 4; ++t) {
        uint4 u = *(const uint4*)(kp + t * 8);
        float a0, a1;
        unpack2(u.x, a0, a1); s += q[t * 8 + 0] * a0 + q[t * 8 + 1] * a1;
        unpack2(u.y, a0, a1); s += q[t * 8 + 2] * a0 + q[t * 8 + 3] * a1;
        unpack2(u.z, a0, a1); s += q[t * 8 + 4] * a0 + q[t * 8 + 5] * a1;
        unpack2(u.w, a0, a1); s += q[t * 8 + 6] * a0 + q[t * 8 + 7] * a1;
      }
      sc[i * 3 + j] = ok ? s * 0.17677669529663687f : 0.f;   // 32^-0.5
    }
  }

  float mx = sc[0];
#pragma unroll
  for (int t = 1; t < 9; ++t) mx = fmaxf(mx, sc[t]);
  float wgt[9], sum = 0.f;
#pragma unroll
  for (int t = 0; t < 9; ++t) { wgt[t] = __expf(sc[t] - mx); sum += wgt[t]; }
  const float inv = 1.f / sum;

  float o[32];
#pragma unroll
  for (int t = 0; t < 32; ++t) o[t] = 0.f;
#pragma unroll
  for (int i = 0; i < 3; ++i) {
#pragma unroll
    for (int j = 0; j < 3; ++j) {
      const int hh = h + (i - 1) * dil;
      const int ww = w + (j - 1) * dil;
      const bool ok = ((unsigned)hh < 128u) && ((unsigned)ww < 128u);
      const int hcl = min(max(hh, 0), 127);
      const int wcl = min(max(ww, 0), 127);
      const unsigned short* vp =
          qkv + (size_t)((((b << 7) | hcl) << 7) | wcl) * 768 + 512 + choff;
      const float wv = ok ? wgt[i * 3 + j] * inv : 0.f;   // V zero-padded
#pragma unroll
      for (int t = 0; t < 4; ++t) {
        uint4 u = *(const uint4*)(vp + t * 8);
        float a0, a1;
        unpack2(u.x, a0, a1); o[t * 8 + 0] += wv * a0; o[t * 8 + 1] += wv * a1;
        unpack2(u.y, a0, a1); o[t * 8 + 2] += wv * a0; o[t * 8 + 3] += wv * a1;
        unpack2(u.z, a0, a1); o[t * 8 + 4] += wv * a0; o[t * 8 + 5] += wv * a1;
        unpack2(u.w, a0, a1); o[t * 8 + 6] += wv * a0; o[t * 8 + 7] += wv * a1;
      }
    }
  }

  unsigned short* op = xo + (size_t)pixel * 256 + choff;
#pragma unroll
  for (int t = 0; t < 4; ++t) {
    uint4 u;
    u.x = pk2bf(o[t * 8 + 0], o[t * 8 + 1]);
    u.y = pk2bf(o[t * 8 + 2], o[t * 8 + 3]);
    u.z = pk2bf(o[t * 8 + 4], o[t * 8 + 5]);
    u.w = pk2bf(o[t * 8 + 6], o[t * 8 + 7]);
    *(uint4*)(op + t * 8) = u;
  }
}

// ---------------------------------------------------------------------------
extern "C" void kernel_launch(void* const* d_in, const int* in_sizes, int n_in,
                              void* d_out, int out_size, void* d_ws, size_t ws_size,
                              hipStream_t stream) {
  const float* x     = (const float*)d_in[0];
  const float* Wqkv  = (const float*)d_in[1];
  const float* Wproj = (const float*)d_in[2];
  const float* bproj = (const float*)d_in[3];

  const int M = 4 * 128 * 128;   // 65536 pixels
  const int C = 256;

  // workspace layout (bf16 ushorts): xb | qkv | xo | Wqkv_b | Wproj_b  (~161 MB)
  unsigned short* xb     = (unsigned short*)d_ws;
  unsigned short* qkvb   = xb + (size_t)M * C;
  unsigned short* xob    = qkvb + (size_t)M * 3 * C;
  unsigned short* wqkvb  = xob + (size_t)M * C;
  unsigned short* wprojb = wqkvb + (size_t)3 * C * C;

  cvt_f32_to_bf16<<<(M * C / 8 + 255) / 256, 256, 0, stream>>>(x, xb, M * C);
  cvt_f32_to_bf16<<<(3 * C * C / 8 + 255) / 256, 256, 0, stream>>>(Wqkv, wqkvb, 3 * C * C);
  cvt_f32_to_bf16<<<(C * C / 8 + 255) / 256, 256, 0, stream>>>(Wproj, wprojb, C * C);

  gemm_bt<0><<<(M / 128) * (3 * C / 128), 256, 0, stream>>>(
      xb, wqkvb, (void*)qkvb, nullptr, 3 * C, 3 * C / 128);

  attn_kernel<<<(M * 8) / 256, 256, 0, stream>>>(qkvb, xob);

  gemm_bt<1><<<(M / 128) * (C / 128), 256, 0, stream>>>(
      xob, wprojb, d_out, bproj, C, C / 128);
}

// Round 9
// 126.784 us; speedup vs baseline: 1.0525x; 1.0525x over previous
//
#include <hip/hip_runtime.h>
#include <stdint.h>

// ---------------------------------------------------------------------------
// MultiDilatelocalAttention (B=4, H=W=128, C=256, heads=8, K=3, dil={2,3})
//   1) qkv = x @ Wqkv^T            (bf16 MFMA GEMM, M=65536 N=768 K=256)
//   2) dilated 3x3 local attention (LDS-tiled, one block = 16x16 px x combo)
//   3) out = xo @ Wproj^T + bproj  (bf16 MFMA GEMM, fp32 out)
// GEMM (R7): BK=32, counted-vmcnt depth-2 pipeline, T1 XCD swizzle, T2 XOR
// swizzle, LDS-staged epilogue.
// attn R9: per-thread global taps were latency-bound at ~50us in every
// variant (R5/R6/R8: 19 dependent L2 round trips/thread; ILP<->occupancy
// wash proven by R8's VGPR 44->88 + occ 39->18 at equal dur). Now each block
// stages its (16+2d)^2 halo K+V tile into LDS ONCE (zero-filled OOB => the
// zero-pad unfold is baked into the data; compute phase is branch-free),
// then 72 tap reads are ds_reads. Layout [8 planes][485 px][16B]: odd plane
// stride => conflict-free staging writes; granule-plane reads hit the b128
// bandwidth floor. Dots as 4 per-granule f32x2 partials (v_pk_fma_f32).
// ---------------------------------------------------------------------------

typedef __attribute__((ext_vector_type(8))) short bf16x8;
typedef __attribute__((ext_vector_type(4))) float f32x4;
typedef __attribute__((ext_vector_type(2))) float f32x2;

__device__ __forceinline__ f32x2 up2(unsigned u) {
  union { unsigned u; float f; } a, b;
  a.u = u << 16;
  b.u = u & 0xffff0000u;
  return (f32x2){a.f, b.f};
}
__device__ __forceinline__ unsigned short f2bf(float f) {
  union { float f; unsigned u; } x; x.f = f;
  unsigned r = x.u + 0x7fffu + ((x.u >> 16) & 1u);   // RNE
  return (unsigned short)(r >> 16);
}
__device__ __forceinline__ unsigned pk2bf(float a, float b) {
  return (unsigned)f2bf(a) | ((unsigned)f2bf(b) << 16);
}

// ------------------------------- fp32 -> bf16 ------------------------------
__global__ __launch_bounds__(256) void cvt_f32_to_bf16(
    const float* __restrict__ src, unsigned short* __restrict__ dst, int n) {
  int i = (blockIdx.x * 256 + threadIdx.x) * 8;
  if (i + 8 <= n) {
    const float4* s = (const float4*)(src + i);
    float4 a = s[0], b = s[1];
    uint4 o;
    o.x = pk2bf(a.x, a.y); o.y = pk2bf(a.z, a.w);
    o.z = pk2bf(b.x, b.y); o.w = pk2bf(b.z, b.w);
    *(uint4*)(dst + i) = o;
  } else {
    for (; i < n; ++i) dst[i] = f2bf(src[i]);
  }
}

// ------------------------- GEMM: C = A @ B^T (bf16) ------------------------
#define BARX()                                                \
  do {                                                        \
    asm volatile("s_waitcnt lgkmcnt(0)" ::: "memory");        \
    __builtin_amdgcn_s_barrier();                             \
    __builtin_amdgcn_sched_barrier(0);                        \
  } while (0)
#define WAITVM(n)                                             \
  do {                                                        \
    asm volatile("s_waitcnt vmcnt(" #n ")" ::: "memory");     \
    __builtin_amdgcn_sched_barrier(0);                        \
  } while (0)

template <int OUTF32>
__global__ __launch_bounds__(256) void gemm_bt(
    const unsigned short* __restrict__ A, const unsigned short* __restrict__ B,
    void* __restrict__ Cout, const float* __restrict__ bias,
    int N, int NT) {
  // K-loop: A0[0,4096) B0[4096,8192) A1[8192,12288) B1[12288,16384) ushorts,
  // each tile 128x32 bf16 = 8 KB. Epilogue reuses [0,17408) = 34816 B total.
  __shared__ __align__(16) unsigned short lds[17408];

  const int tid  = threadIdx.x;
  const int lane = tid & 63;
  const int wv   = tid >> 6;
  const int wr   = wv >> 1;   // wave row (0..1)
  const int wc   = wv & 1;    // wave col (0..1)

  // XCD-chunked bijective swizzle (gridDim.x % 8 == 0), N-major tile order.
  const int nwg = gridDim.x;
  const int q8  = nwg >> 3;
  const int nid = (blockIdx.x & 7) * q8 + (blockIdx.x >> 3);
  const int n0  = (nid % NT) * 128;
  const int m0  = (nid / NT) * 128;

  // staging (BK=32): per issue `it` (0..1), wave wv writes 1 KB linearly at
  // elem = it*2048 + wv*512 + l*8 -> row = it*64 + wv*16 + (l>>2), gran = l&3.
  // T2: lane fetches global granule (l&3)^key, key=(row>>1)&3=(l>>3)&3.
  const int stg_row = wv * 16 + (lane >> 2);
  const int stg_k   = ((lane & 3) ^ ((lane >> 3) & 3)) * 8;
  const unsigned short* Ag = A + (size_t)(m0 + stg_row) * 256 + stg_k;
  const unsigned short* Bg = B + (size_t)(n0 + stg_row) * 256 + stg_k;

  f32x4 acc[4][4];
#pragma unroll
  for (int i = 0; i < 4; ++i)
#pragma unroll
    for (int j = 0; j < 4; ++j) acc[i][j] = (f32x4){0.f, 0.f, 0.f, 0.f};

  const int a_r = lane & 15;   // row within 16x16 fragment (row&15)

#define STAGE(buf, kt)                                                         \
  do {                                                                         \
    const unsigned short* Asrc = Ag + (kt) * 32;                               \
    const unsigned short* Bsrc = Bg + (kt) * 32;                               \
    _Pragma("unroll")                                                          \
    for (int it = 0; it < 2; ++it) {                                           \
      __builtin_amdgcn_global_load_lds(                                        \
          (const __attribute__((address_space(1))) void*)(Asrc + (size_t)it * 64 * 256), \
          (__attribute__((address_space(3))) void*)&lds[(buf) * 8192 + it * 2048 + wv * 512], \
          16, 0, 0);                                                           \
      __builtin_amdgcn_global_load_lds(                                        \
          (const __attribute__((address_space(1))) void*)(Bsrc + (size_t)it * 64 * 256), \
          (__attribute__((address_space(3))) void*)&lds[(buf) * 8192 + 4096 + it * 2048 + wv * 512], \
          16, 0, 0);                                                           \
    }                                                                          \
  } while (0)

// read swizzle: nominal gran = lane>>4, key = (row>>1)&3 = (lane>>1)&3
// (all fragment row bases are multiples of 16, row = base + (lane&15)).
#define COMPUTE(buf)                                                           \
  do {                                                                         \
    const int gsw = (((lane >> 4) ^ ((lane >> 1) & 3))) * 8;                   \
    bf16x8 af[4], bfr[4];                                                      \
    _Pragma("unroll")                                                          \
    for (int mi = 0; mi < 4; ++mi)                                             \
      af[mi] = *(const bf16x8*)&lds[(buf) * 8192 + (wr * 64 + mi * 16 + a_r) * 32 + gsw]; \
    _Pragma("unroll")                                                          \
    for (int ni = 0; ni < 4; ++ni)                                             \
      bfr[ni] = *(const bf16x8*)&lds[(buf) * 8192 + 4096 + (wc * 64 + ni * 16 + a_r) * 32 + gsw]; \
    _Pragma("unroll")                                                          \
    for (int mi = 0; mi < 4; ++mi)                                             \
      _Pragma("unroll")                                                        \
      for (int ni = 0; ni < 4; ++ni)                                           \
        acc[mi][ni] = __builtin_amdgcn_mfma_f32_16x16x32_bf16(                 \
            af[mi], bfr[ni], acc[mi][ni], 0, 0, 0);                            \
  } while (0)

  // Depth-2 prefetch, 4 loads/wave per STAGE; counted vmcnt, never 0 until
  // the final tile. 8 K-tiles rotate buffers 0,1,0,1,...
  STAGE(0, 0);
  STAGE(1, 1);
  WAITVM(4);  BARX();
  COMPUTE(0);  BARX();
  STAGE(0, 2); WAITVM(4); BARX();
  COMPUTE(1);  BARX();
  STAGE(1, 3); WAITVM(4); BARX();
  COMPUTE(0);  BARX();
  STAGE(0, 4); WAITVM(4); BARX();
  COMPUTE(1);  BARX();
  STAGE(1, 5); WAITVM(4); BARX();
  COMPUTE(0);  BARX();
  STAGE(0, 6); WAITVM(4); BARX();
  COMPUTE(1);  BARX();
  STAGE(1, 7); WAITVM(4); BARX();
  COMPUTE(0);  BARX();
  WAITVM(0);   BARX();
  COMPUTE(1);  BARX();   // LDS about to be reused by epilogue

  // ------------------- LDS-staged coalesced epilogue -------------------
  const int cl = wc * 64 + a_r;              // local col base
  const int rl = wr * 64 + (lane >> 4) * 4;  // local row base
  if (!OUTF32) {
    // 128 rows x (128+8) bf16 = 17408 ushorts (16B-aligned rows, bank spread)
    unsigned short* eb = &lds[0];
#pragma unroll
    for (int ni = 0; ni < 4; ++ni)
#pragma unroll
      for (int mi = 0; mi < 4; ++mi)
#pragma unroll
        for (int r = 0; r < 4; ++r)
          eb[(rl + mi * 16 + r) * 136 + cl + ni * 16] = f2bf(acc[mi][ni][r]);
    BARX();   // lgkmcnt(0) drain inside: publishes ds_writes to all waves
    unsigned short* C = (unsigned short*)Cout;
#pragma unroll
    for (int p = 0; p < 8; ++p) {
      const int idx = p * 256 + tid;
      const int row = idx >> 4;
      const int seg = idx & 15;
      uint4 v = *(const uint4*)&eb[row * 136 + seg * 8];
      *(uint4*)&C[(size_t)(m0 + row) * N + n0 + seg * 8] = v;
    }
  } else {
    // f32: two 64-row halves of (128+4)-f32-stride rows (33792 B each)
    float* ef = (float*)&lds[0];
    float* C = (float*)Cout;
    float bv[4];
#pragma unroll
    for (int ni = 0; ni < 4; ++ni) bv[ni] = bias[n0 + wc * 64 + ni * 16 + a_r];
#pragma unroll
    for (int half = 0; half < 2; ++half) {
      if (wr == half) {
        const int rb = (lane >> 4) * 4;   // local row within the half
#pragma unroll
        for (int ni = 0; ni < 4; ++ni)
#pragma unroll
          for (int mi = 0; mi < 4; ++mi)
#pragma unroll
            for (int r = 0; r < 4; ++r)
              ef[(rb + mi * 16 + r) * 132 + wc * 64 + ni * 16 + a_r] =
                  acc[mi][ni][r] + bv[ni];
      }
      BARX();   // lgkmcnt(0) drain inside
#pragma unroll
      for (int p = 0; p < 8; ++p) {
        const int idx = p * 256 + tid;
        const int row = idx >> 5;
        const int seg = idx & 31;
        f32x4 v = *(const f32x4*)&ef[row * 132 + seg * 4];
        *(f32x4*)&C[(size_t)(m0 + half * 64 + row) * N + n0 + seg * 4] = v;
      }
      BARX();
    }
  }
#undef STAGE
#undef COMPUTE
}

// --------------------------- dilated local attention -----------------------
// One block = 16x16 pixel tile x one combo. K+V halo tile staged in LDS with
// OOB pixels ZERO-FILLED (exact zero-pad-unfold semantics; compute phase is
// branch-free). LDS layout: [plane 0..7][485][16B], planes 0-3 = K granules
// (ch 8*gr..8*gr+7), planes 4-7 = V granules. Tap (i,j) of pixel (ph,pw):
// lp = (ph + i*d)*22 + (pw + j*d), local tile origin is (h0-d, w0-d).
__global__ __launch_bounds__(256) void attn_kernel(
    const unsigned short* __restrict__ qkv, unsigned short* __restrict__ xo) {
  __shared__ __align__(16) unsigned short lds[8 * 485 * 8];   // 62080 B

  const int nwg = gridDim.x;            // 2048, %8 == 0
  const int q8  = nwg >> 3;
  const int nid = (blockIdx.x & 7) * q8 + (blockIdx.x >> 3);
  const int combo = nid & 7;
  const int tw    = (nid >> 3) & 7;
  const int th    = (nid >> 6) & 7;
  const int b     = nid >> 9;
  const int d     = (combo >> 2) ? 3 : 2;     // DILATIONS = (2, 3)
  const int choff = combo * 32;
  const int h0 = th * 16, w0 = tw * 16;
  const int t = threadIdx.x;

  // ---- stage K+V halo tile (22x22 used extent; OOB -> zeros) ----
  // slot = iter*256 + t in [0, 3872): px = slot>>3 (0..483), plane = slot&7.
  // 4 consecutive lanes read one contiguous 64B global segment (coalesced).
#pragma unroll
  for (int it = 0; it < 16; ++it) {
    const int slot  = it * 256 + t;
    const int px    = slot >> 3;
    const int plane = slot & 7;
    const int r = px / 22, c = px % 22;
    const int gh = h0 - d + r;
    const int gw = w0 - d + c;
    const bool live = (slot < 3872);
    const bool ok = live && ((unsigned)gh < 128u) && ((unsigned)gw < 128u);
    const int hcl = min(max(gh, 0), 127);
    const int wcl = min(max(gw, 0), 127);
    const int gp = (((b << 7) | hcl) << 7) | wcl;
    const unsigned short* src = qkv + (size_t)gp * 768 + 256 +
                                (plane >> 2) * 256 + (plane & 3) * 8 + choff;
    uint4 u = *(const uint4*)src;                  // always-valid clamped addr
    if (!ok) u = make_uint4(0u, 0u, 0u, 0u);       // zero-pad semantics
    if (live) *(uint4*)&lds[(plane * 485 + px) * 8] = u;
  }
  __syncthreads();

  // ---- q (32 ch) with softmax scale folded in ----
  const int ph = t >> 4, pw = t & 15;
  const int gp0 = (((b << 7) | (h0 + ph)) << 7) | (w0 + pw);
  const unsigned short* qp = qkv + (size_t)gp0 * 768 + choff;
  f32x2 q2[16];
  {
    uint4 u0 = *(const uint4*)qp;
    uint4 u1 = *(const uint4*)(qp + 8);
    uint4 u2 = *(const uint4*)(qp + 16);
    uint4 u3 = *(const uint4*)(qp + 24);
    const f32x2 s2 = {0.17677669529663687f, 0.17677669529663687f};  // 32^-0.5
    q2[0]  = up2(u0.x) * s2; q2[1]  = up2(u0.y) * s2;
    q2[2]  = up2(u0.z) * s2; q2[3]  = up2(u0.w) * s2;
    q2[4]  = up2(u1.x) * s2; q2[5]  = up2(u1.y) * s2;
    q2[6]  = up2(u1.z) * s2; q2[7]  = up2(u1.w) * s2;
    q2[8]  = up2(u2.x) * s2; q2[9]  = up2(u2.y) * s2;
    q2[10] = up2(u2.z) * s2; q2[11] = up2(u2.w) * s2;
    q2[12] = up2(u3.x) * s2; q2[13] = up2(u3.y) * s2;
    q2[14] = up2(u3.z) * s2; q2[15] = up2(u3.w) * s2;
  }

  // ---- scores: 9 taps from LDS, branch-free (zeros give sc = 0 exactly) ----
  float sc[9];
#pragma unroll
  for (int i = 0; i < 3; ++i) {
#pragma unroll
    for (int j = 0; j < 3; ++j) {
      const int lp = (ph + i * d) * 22 + (pw + j * d);
      const uint4 k0 = *(const uint4*)&lds[(0 * 485 + lp) * 8];
      const uint4 k1 = *(const uint4*)&lds[(1 * 485 + lp) * 8];
      const uint4 k2 = *(const uint4*)&lds[(2 * 485 + lp) * 8];
      const uint4 k3 = *(const uint4*)&lds[(3 * 485 + lp) * 8];
      f32x2 p0 = q2[0] * up2(k0.x);
      p0 += q2[1] * up2(k0.y); p0 += q2[2] * up2(k0.z); p0 += q2[3] * up2(k0.w);
      f32x2 p1 = q2[4] * up2(k1.x);
      p1 += q2[5] * up2(k1.y); p1 += q2[6] * up2(k1.z); p1 += q2[7] * up2(k1.w);
      f32x2 p2 = q2[8] * up2(k2.x);
      p2 += q2[9] * up2(k2.y); p2 += q2[10] * up2(k2.z); p2 += q2[11] * up2(k2.w);
      f32x2 p3 = q2[12] * up2(k3.x);
      p3 += q2[13] * up2(k3.y); p3 += q2[14] * up2(k3.z); p3 += q2[15] * up2(k3.w);
      const f32x2 s = (p0 + p1) + (p2 + p3);
      sc[i * 3 + j] = s.x + s.y;
    }
  }

  // ---- softmax over 9 ----
  float mx = sc[0];
#pragma unroll
  for (int k = 1; k < 9; ++k) mx = fmaxf(mx, sc[k]);
  float sum = 0.f;
#pragma unroll
  for (int k = 0; k < 9; ++k) { sc[k] = __expf(sc[k] - mx); sum += sc[k]; }
  const float inv = 1.f / sum;

  // ---- weighted V accumulate (planes 4..7), branch-free ----
  f32x2 o2[16];
#pragma unroll
  for (int k = 0; k < 16; ++k) o2[k] = (f32x2){0.f, 0.f};
#pragma unroll
  for (int i = 0; i < 3; ++i) {
#pragma unroll
    for (int j = 0; j < 3; ++j) {
      const int lp = (ph + i * d) * 22 + (pw + j * d);
      const uint4 v0 = *(const uint4*)&lds[(4 * 485 + lp) * 8];
      const uint4 v1 = *(const uint4*)&lds[(5 * 485 + lp) * 8];
      const uint4 v2 = *(const uint4*)&lds[(6 * 485 + lp) * 8];
      const uint4 v3 = *(const uint4*)&lds[(7 * 485 + lp) * 8];
      const float wv = sc[i * 3 + j] * inv;
      const f32x2 w2 = {wv, wv};
      o2[0]  += w2 * up2(v0.x); o2[1]  += w2 * up2(v0.y);
      o2[2]  += w2 * up2(v0.z); o2[3]  += w2 * up2(v0.w);
      o2[4]  += w2 * up2(v1.x); o2[5]  += w2 * up2(v1.y);
      o2[6]  += w2 * up2(v1.z); o2[7]  += w2 * up2(v1.w);
      o2[8]  += w2 * up2(v2.x); o2[9]  += w2 * up2(v2.y);
      o2[10] += w2 * up2(v2.z); o2[11] += w2 * up2(v2.w);
      o2[12] += w2 * up2(v3.x); o2[13] += w2 * up2(v3.y);
      o2[14] += w2 * up2(v3.z); o2[15] += w2 * up2(v3.w);
    }
  }

  // ---- store 32 ch bf16 ----
  unsigned short* op = xo + (size_t)gp0 * 256 + choff;
  uint4 s0, s1, s2o, s3o;
  s0.x  = pk2bf(o2[0].x,  o2[0].y);  s0.y  = pk2bf(o2[1].x,  o2[1].y);
  s0.z  = pk2bf(o2[2].x,  o2[2].y);  s0.w  = pk2bf(o2[3].x,  o2[3].y);
  s1.x  = pk2bf(o2[4].x,  o2[4].y);  s1.y  = pk2bf(o2[5].x,  o2[5].y);
  s1.z  = pk2bf(o2[6].x,  o2[6].y);  s1.w  = pk2bf(o2[7].x,  o2[7].y);
  s2o.x = pk2bf(o2[8].x,  o2[8].y);  s2o.y = pk2bf(o2[9].x,  o2[9].y);
  s2o.z = pk2bf(o2[10].x, o2[10].y); s2o.w = pk2bf(o2[11].x, o2[11].y);
  s3o.x = pk2bf(o2[12].x, o2[12].y); s3o.y = pk2bf(o2[13].x, o2[13].y);
  s3o.z = pk2bf(o2[14].x, o2[14].y); s3o.w = pk2bf(o2[15].x, o2[15].y);
  *(uint4*)op        = s0;
  *(uint4*)(op + 8)  = s1;
  *(uint4*)(op + 16) = s2o;
  *(uint4*)(op + 24) = s3o;
}

// ---------------------------------------------------------------------------
extern "C" void kernel_launch(void* const* d_in, const int* in_sizes, int n_in,
                              void* d_out, int out_size, void* d_ws, size_t ws_size,
                              hipStream_t stream) {
  const float* x     = (const float*)d_in[0];
  const float* Wqkv  = (const float*)d_in[1];
  const float* Wproj = (const float*)d_in[2];
  const float* bproj = (const float*)d_in[3];

  const int M = 4 * 128 * 128;   // 65536 pixels
  const int C = 256;

  // workspace layout (bf16 ushorts): xb | qkv | xo | Wqkv_b | Wproj_b  (~161 MB)
  unsigned short* xb     = (unsigned short*)d_ws;
  unsigned short* qkvb   = xb + (size_t)M * C;
  unsigned short* xob    = qkvb + (size_t)M * 3 * C;
  unsigned short* wqkvb  = xob + (size_t)M * C;
  unsigned short* wprojb = wqkvb + (size_t)3 * C * C;

  cvt_f32_to_bf16<<<(M * C / 8 + 255) / 256, 256, 0, stream>>>(x, xb, M * C);
  cvt_f32_to_bf16<<<(3 * C * C / 8 + 255) / 256, 256, 0, stream>>>(Wqkv, wqkvb, 3 * C * C);
  cvt_f32_to_bf16<<<(C * C / 8 + 255) / 256, 256, 0, stream>>>(Wproj, wprojb, C * C);

  gemm_bt<0><<<(M / 128) * (3 * C / 128), 256, 0, stream>>>(
      xb, wqkvb, (void*)qkvb, nullptr, 3 * C, 3 * C / 128);

  // 4 batches x 8x8 tiles x 8 combos = 2048 blocks, 256 threads (16x16 px)
  attn_kernel<<<2048, 256, 0, stream>>>(qkvb, xob);

  gemm_bt<1><<<(M / 128) * (C / 128), 256, 0, stream>>>(
      xob, wprojb, d_out, bproj, C, C / 128);
}

// Round 10
// 123.958 us; speedup vs baseline: 1.0765x; 1.0228x over previous
//
#include <hip/hip_runtime.h>
#include <stdint.h>

// ---------------------------------------------------------------------------
// MultiDilatelocalAttention (B=4, H=W=128, C=256, heads=8, K=3, dil={2,3})
//   1) qkv = x @ Wqkv^T            (bf16 MFMA GEMM, M=65536 N=768 K=256)
//   2) dilated 3x3 local attention (LDS-tiled, one block = 16x16 px x combo)
//   3) out = xo @ Wproj^T + bproj  (bf16 MFMA GEMM, fp32 out)
// GEMM (R7): BK=32, counted-vmcnt depth-2 pipeline, T1 XCD swizzle, T2 XOR
// swizzle, LDS-staged epilogue.
// attn R10: R9 was residency-limited (62.5KB LDS -> 2 blocks/CU, occ 17%,
// VALU 19us + LDS 11us both <50% duty of 45us). Now ONE 4-plane buffer
// (31KB) reused K-then-V -> 5 blocks/CU. V loads issued into registers
// BEFORE the score phase (T14 async-stage split: clamped unconditional
// loads; zero-select deferred to the LDS write so the vmcnt wait lands
// after ~400cy of score VALU). Staging: plane = t&3 (256%4==0), px =
// it*64+(t>>2); s_gp/s_ok computed once, reused by both phases.
// ---------------------------------------------------------------------------

typedef __attribute__((ext_vector_type(8))) short bf16x8;
typedef __attribute__((ext_vector_type(4))) float f32x4;
typedef __attribute__((ext_vector_type(2))) float f32x2;

__device__ __forceinline__ f32x2 up2(unsigned u) {
  union { unsigned u; float f; } a, b;
  a.u = u << 16;
  b.u = u & 0xffff0000u;
  return (f32x2){a.f, b.f};
}
__device__ __forceinline__ unsigned short f2bf(float f) {
  union { float f; unsigned u; } x; x.f = f;
  unsigned r = x.u + 0x7fffu + ((x.u >> 16) & 1u);   // RNE
  return (unsigned short)(r >> 16);
}
__device__ __forceinline__ unsigned pk2bf(float a, float b) {
  return (unsigned)f2bf(a) | ((unsigned)f2bf(b) << 16);
}

// ------------------------------- fp32 -> bf16 ------------------------------
__global__ __launch_bounds__(256) void cvt_f32_to_bf16(
    const float* __restrict__ src, unsigned short* __restrict__ dst, int n) {
  int i = (blockIdx.x * 256 + threadIdx.x) * 8;
  if (i + 8 <= n) {
    const float4* s = (const float4*)(src + i);
    float4 a = s[0], b = s[1];
    uint4 o;
    o.x = pk2bf(a.x, a.y); o.y = pk2bf(a.z, a.w);
    o.z = pk2bf(b.x, b.y); o.w = pk2bf(b.z, b.w);
    *(uint4*)(dst + i) = o;
  } else {
    for (; i < n; ++i) dst[i] = f2bf(src[i]);
  }
}

// ------------------------- GEMM: C = A @ B^T (bf16) ------------------------
#define BARX()                                                \
  do {                                                        \
    asm volatile("s_waitcnt lgkmcnt(0)" ::: "memory");        \
    __builtin_amdgcn_s_barrier();                             \
    __builtin_amdgcn_sched_barrier(0);                        \
  } while (0)
#define WAITVM(n)                                             \
  do {                                                        \
    asm volatile("s_waitcnt vmcnt(" #n ")" ::: "memory");     \
    __builtin_amdgcn_sched_barrier(0);                        \
  } while (0)

template <int OUTF32>
__global__ __launch_bounds__(256) void gemm_bt(
    const unsigned short* __restrict__ A, const unsigned short* __restrict__ B,
    void* __restrict__ Cout, const float* __restrict__ bias,
    int N, int NT) {
  // K-loop: A0[0,4096) B0[4096,8192) A1[8192,12288) B1[12288,16384) ushorts,
  // each tile 128x32 bf16 = 8 KB. Epilogue reuses [0,17408) = 34816 B total.
  __shared__ __align__(16) unsigned short lds[17408];

  const int tid  = threadIdx.x;
  const int lane = tid & 63;
  const int wv   = tid >> 6;
  const int wr   = wv >> 1;   // wave row (0..1)
  const int wc   = wv & 1;    // wave col (0..1)

  // XCD-chunked bijective swizzle (gridDim.x % 8 == 0), N-major tile order.
  const int nwg = gridDim.x;
  const int q8  = nwg >> 3;
  const int nid = (blockIdx.x & 7) * q8 + (blockIdx.x >> 3);
  const int n0  = (nid % NT) * 128;
  const int m0  = (nid / NT) * 128;

  // staging (BK=32): per issue `it` (0..1), wave wv writes 1 KB linearly at
  // elem = it*2048 + wv*512 + l*8 -> row = it*64 + wv*16 + (l>>2), gran = l&3.
  // T2: lane fetches global granule (l&3)^key, key=(row>>1)&3=(l>>3)&3.
  const int stg_row = wv * 16 + (lane >> 2);
  const int stg_k   = ((lane & 3) ^ ((lane >> 3) & 3)) * 8;
  const unsigned short* Ag = A + (size_t)(m0 + stg_row) * 256 + stg_k;
  const unsigned short* Bg = B + (size_t)(n0 + stg_row) * 256 + stg_k;

  f32x4 acc[4][4];
#pragma unroll
  for (int i = 0; i < 4; ++i)
#pragma unroll
    for (int j = 0; j < 4; ++j) acc[i][j] = (f32x4){0.f, 0.f, 0.f, 0.f};

  const int a_r = lane & 15;   // row within 16x16 fragment (row&15)

#define STAGE(buf, kt)                                                         \
  do {                                                                         \
    const unsigned short* Asrc = Ag + (kt) * 32;                               \
    const unsigned short* Bsrc = Bg + (kt) * 32;                               \
    _Pragma("unroll")                                                          \
    for (int it = 0; it < 2; ++it) {                                           \
      __builtin_amdgcn_global_load_lds(                                        \
          (const __attribute__((address_space(1))) void*)(Asrc + (size_t)it * 64 * 256), \
          (__attribute__((address_space(3))) void*)&lds[(buf) * 8192 + it * 2048 + wv * 512], \
          16, 0, 0);                                                           \
      __builtin_amdgcn_global_load_lds(                                        \
          (const __attribute__((address_space(1))) void*)(Bsrc + (size_t)it * 64 * 256), \
          (__attribute__((address_space(3))) void*)&lds[(buf) * 8192 + 4096 + it * 2048 + wv * 512], \
          16, 0, 0);                                                           \
    }                                                                          \
  } while (0)

// read swizzle: nominal gran = lane>>4, key = (row>>1)&3 = (lane>>1)&3
// (all fragment row bases are multiples of 16, row = base + (lane&15)).
#define COMPUTE(buf)                                                           \
  do {                                                                         \
    const int gsw = (((lane >> 4) ^ ((lane >> 1) & 3))) * 8;                   \
    bf16x8 af[4], bfr[4];                                                      \
    _Pragma("unroll")                                                          \
    for (int mi = 0; mi < 4; ++mi)                                             \
      af[mi] = *(const bf16x8*)&lds[(buf) * 8192 + (wr * 64 + mi * 16 + a_r) * 32 + gsw]; \
    _Pragma("unroll")                                                          \
    for (int ni = 0; ni < 4; ++ni)                                             \
      bfr[ni] = *(const bf16x8*)&lds[(buf) * 8192 + 4096 + (wc * 64 + ni * 16 + a_r) * 32 + gsw]; \
    _Pragma("unroll")                                                          \
    for (int mi = 0; mi < 4; ++mi)                                             \
      _Pragma("unroll")                                                        \
      for (int ni = 0; ni < 4; ++ni)                                           \
        acc[mi][ni] = __builtin_amdgcn_mfma_f32_16x16x32_bf16(                 \
            af[mi], bfr[ni], acc[mi][ni], 0, 0, 0);                            \
  } while (0)

  // Depth-2 prefetch, 4 loads/wave per STAGE; counted vmcnt, never 0 until
  // the final tile. 8 K-tiles rotate buffers 0,1,0,1,...
  STAGE(0, 0);
  STAGE(1, 1);
  WAITVM(4);  BARX();
  COMPUTE(0);  BARX();
  STAGE(0, 2); WAITVM(4); BARX();
  COMPUTE(1);  BARX();
  STAGE(1, 3); WAITVM(4); BARX();
  COMPUTE(0);  BARX();
  STAGE(0, 4); WAITVM(4); BARX();
  COMPUTE(1);  BARX();
  STAGE(1, 5); WAITVM(4); BARX();
  COMPUTE(0);  BARX();
  STAGE(0, 6); WAITVM(4); BARX();
  COMPUTE(1);  BARX();
  STAGE(1, 7); WAITVM(4); BARX();
  COMPUTE(0);  BARX();
  WAITVM(0);   BARX();
  COMPUTE(1);  BARX();   // LDS about to be reused by epilogue

  // ------------------- LDS-staged coalesced epilogue -------------------
  const int cl = wc * 64 + a_r;              // local col base
  const int rl = wr * 64 + (lane >> 4) * 4;  // local row base
  if (!OUTF32) {
    // 128 rows x (128+8) bf16 = 17408 ushorts (16B-aligned rows, bank spread)
    unsigned short* eb = &lds[0];
#pragma unroll
    for (int ni = 0; ni < 4; ++ni)
#pragma unroll
      for (int mi = 0; mi < 4; ++mi)
#pragma unroll
        for (int r = 0; r < 4; ++r)
          eb[(rl + mi * 16 + r) * 136 + cl + ni * 16] = f2bf(acc[mi][ni][r]);
    BARX();   // lgkmcnt(0) drain inside: publishes ds_writes to all waves
    unsigned short* C = (unsigned short*)Cout;
#pragma unroll
    for (int p = 0; p < 8; ++p) {
      const int idx = p * 256 + tid;
      const int row = idx >> 4;
      const int seg = idx & 15;
      uint4 v = *(const uint4*)&eb[row * 136 + seg * 8];
      *(uint4*)&C[(size_t)(m0 + row) * N + n0 + seg * 8] = v;
    }
  } else {
    // f32: two 64-row halves of (128+4)-f32-stride rows (33792 B each)
    float* ef = (float*)&lds[0];
    float* C = (float*)Cout;
    float bv[4];
#pragma unroll
    for (int ni = 0; ni < 4; ++ni) bv[ni] = bias[n0 + wc * 64 + ni * 16 + a_r];
#pragma unroll
    for (int half = 0; half < 2; ++half) {
      if (wr == half) {
        const int rb = (lane >> 4) * 4;   // local row within the half
#pragma unroll
        for (int ni = 0; ni < 4; ++ni)
#pragma unroll
          for (int mi = 0; mi < 4; ++mi)
#pragma unroll
            for (int r = 0; r < 4; ++r)
              ef[(rb + mi * 16 + r) * 132 + wc * 64 + ni * 16 + a_r] =
                  acc[mi][ni][r] + bv[ni];
      }
      BARX();   // lgkmcnt(0) drain inside
#pragma unroll
      for (int p = 0; p < 8; ++p) {
        const int idx = p * 256 + tid;
        const int row = idx >> 5;
        const int seg = idx & 31;
        f32x4 v = *(const f32x4*)&ef[row * 132 + seg * 4];
        *(f32x4*)&C[(size_t)(m0 + half * 64 + row) * N + n0 + seg * 4] = v;
      }
      BARX();
    }
  }
#undef STAGE
#undef COMPUTE
}

// --------------------------- dilated local attention -----------------------
// One block = 16x16 pixel tile x one combo. ONE 4-plane LDS buffer (31KB)
// reused K-then-V: stage K -> sync -> scores (V global loads in flight) ->
// sync -> write V -> sync -> PV. OOB pixels zero-filled (exact zero-pad
// unfold; compute is branch-free). Layout [plane 0..3][485 px][16B],
// plane = granule (ch 8*plane..8*plane+7). Tap (i,j) of pixel (ph,pw):
// lp = (ph+i*d)*22 + (pw+j*d); tile origin (h0-d, w0-d).
__global__ __launch_bounds__(256) void attn_kernel(
    const unsigned short* __restrict__ qkv, unsigned short* __restrict__ xo) {
  __shared__ __align__(16) unsigned short lds[4 * 485 * 8];   // 31040 B

  const int nwg = gridDim.x;            // 2048, %8 == 0
  const int q8  = nwg >> 3;
  const int nid = (blockIdx.x & 7) * q8 + (blockIdx.x >> 3);
  const int combo = nid & 7;
  const int tw    = (nid >> 3) & 7;
  const int th    = (nid >> 6) & 7;
  const int b     = nid >> 9;
  const int d     = (combo >> 2) ? 3 : 2;     // DILATIONS = (2, 3)
  const int choff = combo * 32;
  const int h0 = th * 16, w0 = tw * 16;
  const int t = threadIdx.x;

  // staging geometry (both K and V): plane = t&3 (const: 256%4==0),
  // px = it*64 + (t>>2). 485*4 slots; it<7 always live; it==7 live iff t<144.
  const int plane = t & 3;
  const int t4    = t >> 2;
  const int choffp = choff + plane * 8;

  // per-slot pixel index + validity, computed ONCE
  int  s_gp[8];
  bool s_ok[8];
#pragma unroll
  for (int it = 0; it < 8; ++it) {
    const int px = it * 64 + t4;        // may exceed 483 on it==7 (unused)
    const int r = px / 22, c = px % 22; // magic-mul
    const int gh = h0 - d + r;
    const int gw = w0 - d + c;
    s_ok[it] = ((unsigned)gh < 128u) && ((unsigned)gw < 128u);
    const int hcl = min(max(gh, 0), 127);
    const int wcl = min(max(gw, 0), 127);
    s_gp[it] = (((b << 7) | hcl) << 7) | wcl;
  }

  const uint4 zz = make_uint4(0u, 0u, 0u, 0u);

  // ---- q loads issued first (consumed pre-scores) ----
  const int ph = t >> 4, pw = t & 15;
  const int gp0 = (((b << 7) | (h0 + ph)) << 7) | (w0 + pw);
  const unsigned short* qp = qkv + (size_t)gp0 * 768 + choff;
  uint4 uq0 = *(const uint4*)qp;
  uint4 uq1 = *(const uint4*)(qp + 8);
  uint4 uq2 = *(const uint4*)(qp + 16);
  uint4 uq3 = *(const uint4*)(qp + 24);

  // ---- stage K (planes = granules of 8 ch) ----
#pragma unroll
  for (int it = 0; it < 8; ++it) {
    uint4 u = *(const uint4*)(qkv + (size_t)s_gp[it] * 768 + 256 + choffp);
    if (!s_ok[it]) u = zz;
    if (it < 7 || t < 144) *(uint4*)&lds[(plane * 485 + it * 64 + t4) * 8] = u;
  }
  __syncthreads();

  // ---- T14: issue V loads into regs BEFORE the score phase ----
  uint4 vr[8];
#pragma unroll
  for (int it = 0; it < 8; ++it)
    vr[it] = *(const uint4*)(qkv + (size_t)s_gp[it] * 768 + 512 + choffp);

  // ---- q unpack with softmax scale folded in ----
  f32x2 q2[16];
  {
    const f32x2 s2 = {0.17677669529663687f, 0.17677669529663687f};  // 32^-0.5
    q2[0]  = up2(uq0.x) * s2; q2[1]  = up2(uq0.y) * s2;
    q2[2]  = up2(uq0.z) * s2; q2[3]  = up2(uq0.w) * s2;
    q2[4]  = up2(uq1.x) * s2; q2[5]  = up2(uq1.y) * s2;
    q2[6]  = up2(uq1.z) * s2; q2[7]  = up2(uq1.w) * s2;
    q2[8]  = up2(uq2.x) * s2; q2[9]  = up2(uq2.y) * s2;
    q2[10] = up2(uq2.z) * s2; q2[11] = up2(uq2.w) * s2;
    q2[12] = up2(uq3.x) * s2; q2[13] = up2(uq3.y) * s2;
    q2[14] = up2(uq3.z) * s2; q2[15] = up2(uq3.w) * s2;
  }

  // ---- scores: 9 taps from LDS, branch-free (zeros give sc = 0 exactly) ----
  float sc[9];
#pragma unroll
  for (int i = 0; i < 3; ++i) {
#pragma unroll
    for (int j = 0; j < 3; ++j) {
      const int lp = (ph + i * d) * 22 + (pw + j * d);
      const uint4 k0 = *(const uint4*)&lds[(0 * 485 + lp) * 8];
      const uint4 k1 = *(const uint4*)&lds[(1 * 485 + lp) * 8];
      const uint4 k2 = *(const uint4*)&lds[(2 * 485 + lp) * 8];
      const uint4 k3 = *(const uint4*)&lds[(3 * 485 + lp) * 8];
      f32x2 p0 = q2[0] * up2(k0.x);
      p0 += q2[1] * up2(k0.y); p0 += q2[2] * up2(k0.z); p0 += q2[3] * up2(k0.w);
      f32x2 p1 = q2[4] * up2(k1.x);
      p1 += q2[5] * up2(k1.y); p1 += q2[6] * up2(k1.z); p1 += q2[7] * up2(k1.w);
      f32x2 p2 = q2[8] * up2(k2.x);
      p2 += q2[9] * up2(k2.y); p2 += q2[10] * up2(k2.z); p2 += q2[11] * up2(k2.w);
      f32x2 p3 = q2[12] * up2(k3.x);
      p3 += q2[13] * up2(k3.y); p3 += q2[14] * up2(k3.z); p3 += q2[15] * up2(k3.w);
      const f32x2 s = (p0 + p1) + (p2 + p3);
      sc[i * 3 + j] = s.x + s.y;
    }
  }

  // ---- softmax over 9 ----
  float mx = sc[0];
#pragma unroll
  for (int k = 1; k < 9; ++k) mx = fmaxf(mx, sc[k]);
  float sum = 0.f;
#pragma unroll
  for (int k = 0; k < 9; ++k) { sc[k] = __expf(sc[k] - mx); sum += sc[k]; }
  const float inv = 1.f / sum;

  // ---- all waves done reading K; overwrite buffer with V ----
  __syncthreads();
#pragma unroll
  for (int it = 0; it < 8; ++it) {
    uint4 u = vr[it];
    if (!s_ok[it]) u = zz;
    if (it < 7 || t < 144) *(uint4*)&lds[(plane * 485 + it * 64 + t4) * 8] = u;
  }
  __syncthreads();

  // ---- weighted V accumulate, branch-free ----
  f32x2 o2[16];
#pragma unroll
  for (int k = 0; k < 16; ++k) o2[k] = (f32x2){0.f, 0.f};
#pragma unroll
  for (int i = 0; i < 3; ++i) {
#pragma unroll
    for (int j = 0; j < 3; ++j) {
      const int lp = (ph + i * d) * 22 + (pw + j * d);
      const uint4 v0 = *(const uint4*)&lds[(0 * 485 + lp) * 8];
      const uint4 v1 = *(const uint4*)&lds[(1 * 485 + lp) * 8];
      const uint4 v2 = *(const uint4*)&lds[(2 * 485 + lp) * 8];
      const uint4 v3 = *(const uint4*)&lds[(3 * 485 + lp) * 8];
      const float wv = sc[i * 3 + j] * inv;
      const f32x2 w2 = {wv, wv};
      o2[0]  += w2 * up2(v0.x); o2[1]  += w2 * up2(v0.y);
      o2[2]  += w2 * up2(v0.z); o2[3]  += w2 * up2(v0.w);
      o2[4]  += w2 * up2(v1.x); o2[5]  += w2 * up2(v1.y);
      o2[6]  += w2 * up2(v1.z); o2[7]  += w2 * up2(v1.w);
      o2[8]  += w2 * up2(v2.x); o2[9]  += w2 * up2(v2.y);
      o2[10] += w2 * up2(v2.z); o2[11] += w2 * up2(v2.w);
      o2[12] += w2 * up2(v3.x); o2[13] += w2 * up2(v3.y);
      o2[14] += w2 * up2(v3.z); o2[15] += w2 * up2(v3.w);
    }
  }

  // ---- store 32 ch bf16 ----
  unsigned short* op = xo + (size_t)gp0 * 256 + choff;
  uint4 s0, s1, s2o, s3o;
  s0.x  = pk2bf(o2[0].x,  o2[0].y);  s0.y  = pk2bf(o2[1].x,  o2[1].y);
  s0.z  = pk2bf(o2[2].x,  o2[2].y);  s0.w  = pk2bf(o2[3].x,  o2[3].y);
  s1.x  = pk2bf(o2[4].x,  o2[4].y);  s1.y  = pk2bf(o2[5].x,  o2[5].y);
  s1.z  = pk2bf(o2[6].x,  o2[6].y);  s1.w  = pk2bf(o2[7].x,  o2[7].y);
  s2o.x = pk2bf(o2[8].x,  o2[8].y);  s2o.y = pk2bf(o2[9].x,  o2[9].y);
  s2o.z = pk2bf(o2[10].x, o2[10].y); s2o.w = pk2bf(o2[11].x, o2[11].y);
  s3o.x = pk2bf(o2[12].x, o2[12].y); s3o.y = pk2bf(o2[13].x, o2[13].y);
  s3o.z = pk2bf(o2[14].x, o2[14].y); s3o.w = pk2bf(o2[15].x, o2[15].y);
  *(uint4*)op        = s0;
  *(uint4*)(op + 8)  = s1;
  *(uint4*)(op + 16) = s2o;
  *(uint4*)(op + 24) = s3o;
}

// ---------------------------------------------------------------------------
extern "C" void kernel_launch(void* const* d_in, const int* in_sizes, int n_in,
                              void* d_out, int out_size, void* d_ws, size_t ws_size,
                              hipStream_t stream) {
  const float* x     = (const float*)d_in[0];
  const float* Wqkv  = (const float*)d_in[1];
  const float* Wproj = (const float*)d_in[2];
  const float* bproj = (const float*)d_in[3];

  const int M = 4 * 128 * 128;   // 65536 pixels
  const int C = 256;

  // workspace layout (bf16 ushorts): xb | qkv | xo | Wqkv_b | Wproj_b  (~161 MB)
  unsigned short* xb     = (unsigned short*)d_ws;
  unsigned short* qkvb   = xb + (size_t)M * C;
  unsigned short* xob    = qkvb + (size_t)M * 3 * C;
  unsigned short* wqkvb  = xob + (size_t)M * C;
  unsigned short* wprojb = wqkvb + (size_t)3 * C * C;

  cvt_f32_to_bf16<<<(M * C / 8 + 255) / 256, 256, 0, stream>>>(x, xb, M * C);
  cvt_f32_to_bf16<<<(3 * C * C / 8 + 255) / 256, 256, 0, stream>>>(Wqkv, wqkvb, 3 * C * C);
  cvt_f32_to_bf16<<<(C * C / 8 + 255) / 256, 256, 0, stream>>>(Wproj, wprojb, C * C);

  gemm_bt<0><<<(M / 128) * (3 * C / 128), 256, 0, stream>>>(
      xb, wqkvb, (void*)qkvb, nullptr, 3 * C, 3 * C / 128);

  // 4 batches x 8x8 tiles x 8 combos = 2048 blocks, 256 threads (16x16 px)
  attn_kernel<<<2048, 256, 0, stream>>>(qkvb, xob);

  gemm_bt<1><<<(M / 128) * (C / 128), 256, 0, stream>>>(
      xob, wprojb, d_out, bproj, C, C / 128);
}

// Round 11
// 115.700 us; speedup vs baseline: 1.1534x; 1.0714x over previous
//
#include <hip/hip_runtime.h>
#include <stdint.h>

// ---------------------------------------------------------------------------
// MultiDilatelocalAttention (B=4, H=W=128, C=256, heads=8, K=3, dil={2,3})
//   1) qkv = x @ Wqkv^T            (bf16 MFMA GEMM, M=65536 N=768 K=256)
//   2) dilated 3x3 local attention (LDS-tiled, lane-pair halves)
//   3) out = xo @ Wproj^T + bproj  (bf16 MFMA GEMM, fp32 out)
// GEMM (R7): BK=32, counted-vmcnt depth-2 pipeline, T1 XCD swizzle, T2 XOR
// swizzle, LDS-staged epilogue.
// attn R11: R10 stuck at 16 waves/CU — VGPR=104 caps occupancy (m69: waves
// halve at 64/128/256) regardless of the LDS win. Now 512-thread blocks,
// 16 ch/thread (lane pair = two halves of one combo; score completed with
// one shfl_xor per tap — math proven in R6, whose slowness was its
// conditional GLOBAL loads, already replaced by the LDS tile). Register
// budget targets the <=64 class: no V-prefetch regs (TLP covers the reload),
// staging addresses recomputed per phase. Same 31KB one-buffer K->V reuse.
// Weight cvts merged into one launch (dsts contiguous in ws).
// ---------------------------------------------------------------------------

typedef __attribute__((ext_vector_type(8))) short bf16x8;
typedef __attribute__((ext_vector_type(4))) float f32x4;
typedef __attribute__((ext_vector_type(2))) float f32x2;

__device__ __forceinline__ f32x2 up2(unsigned u) {
  union { unsigned u; float f; } a, b;
  a.u = u << 16;
  b.u = u & 0xffff0000u;
  return (f32x2){a.f, b.f};
}
__device__ __forceinline__ unsigned short f2bf(float f) {
  union { float f; unsigned u; } x; x.f = f;
  unsigned r = x.u + 0x7fffu + ((x.u >> 16) & 1u);   // RNE
  return (unsigned short)(r >> 16);
}
__device__ __forceinline__ unsigned pk2bf(float a, float b) {
  return (unsigned)f2bf(a) | ((unsigned)f2bf(b) << 16);
}

// ------------------------------- fp32 -> bf16 ------------------------------
__global__ __launch_bounds__(256) void cvt_f32_to_bf16(
    const float* __restrict__ src, unsigned short* __restrict__ dst, int n) {
  int i = (blockIdx.x * 256 + threadIdx.x) * 8;
  if (i + 8 <= n) {
    const float4* s = (const float4*)(src + i);
    float4 a = s[0], b = s[1];
    uint4 o;
    o.x = pk2bf(a.x, a.y); o.y = pk2bf(a.z, a.w);
    o.z = pk2bf(b.x, b.y); o.w = pk2bf(b.z, b.w);
    *(uint4*)(dst + i) = o;
  } else {
    for (; i < n; ++i) dst[i] = f2bf(src[i]);
  }
}

// Both weight matrices in one launch. dst is contiguous (wqkvb|wprojb);
// elements 0..196607 come from Wqkv, the rest from Wproj. 196608/8/256 = 96
// exact -> the source branch is block-uniform.
__global__ __launch_bounds__(256) void cvt_w_both(
    const float* __restrict__ wqkv, const float* __restrict__ wproj,
    unsigned short* __restrict__ dst) {
  const int i = (blockIdx.x * 256 + threadIdx.x) * 8;
  const float* src = (i < 196608) ? (wqkv + i) : (wproj + (i - 196608));
  const float4* s = (const float4*)src;
  float4 a = s[0], b = s[1];
  uint4 o;
  o.x = pk2bf(a.x, a.y); o.y = pk2bf(a.z, a.w);
  o.z = pk2bf(b.x, b.y); o.w = pk2bf(b.z, b.w);
  *(uint4*)(dst + i) = o;
}

// ------------------------- GEMM: C = A @ B^T (bf16) ------------------------
#define BARX()                                                \
  do {                                                        \
    asm volatile("s_waitcnt lgkmcnt(0)" ::: "memory");        \
    __builtin_amdgcn_s_barrier();                             \
    __builtin_amdgcn_sched_barrier(0);                        \
  } while (0)
#define WAITVM(n)                                             \
  do {                                                        \
    asm volatile("s_waitcnt vmcnt(" #n ")" ::: "memory");     \
    __builtin_amdgcn_sched_barrier(0);                        \
  } while (0)

template <int OUTF32>
__global__ __launch_bounds__(256) void gemm_bt(
    const unsigned short* __restrict__ A, const unsigned short* __restrict__ B,
    void* __restrict__ Cout, const float* __restrict__ bias,
    int N, int NT) {
  // K-loop: A0[0,4096) B0[4096,8192) A1[8192,12288) B1[12288,16384) ushorts,
  // each tile 128x32 bf16 = 8 KB. Epilogue reuses [0,17408) = 34816 B total.
  __shared__ __align__(16) unsigned short lds[17408];

  const int tid  = threadIdx.x;
  const int lane = tid & 63;
  const int wv   = tid >> 6;
  const int wr   = wv >> 1;   // wave row (0..1)
  const int wc   = wv & 1;    // wave col (0..1)

  // XCD-chunked bijective swizzle (gridDim.x % 8 == 0), N-major tile order.
  const int nwg = gridDim.x;
  const int q8  = nwg >> 3;
  const int nid = (blockIdx.x & 7) * q8 + (blockIdx.x >> 3);
  const int n0  = (nid % NT) * 128;
  const int m0  = (nid / NT) * 128;

  // staging (BK=32): per issue `it` (0..1), wave wv writes 1 KB linearly at
  // elem = it*2048 + wv*512 + l*8 -> row = it*64 + wv*16 + (l>>2), gran = l&3.
  // T2: lane fetches global granule (l&3)^key, key=(row>>1)&3=(l>>3)&3.
  const int stg_row = wv * 16 + (lane >> 2);
  const int stg_k   = ((lane & 3) ^ ((lane >> 3) & 3)) * 8;
  const unsigned short* Ag = A + (size_t)(m0 + stg_row) * 256 + stg_k;
  const unsigned short* Bg = B + (size_t)(n0 + stg_row) * 256 + stg_k;

  f32x4 acc[4][4];
#pragma unroll
  for (int i = 0; i < 4; ++i)
#pragma unroll
    for (int j = 0; j < 4; ++j) acc[i][j] = (f32x4){0.f, 0.f, 0.f, 0.f};

  const int a_r = lane & 15;   // row within 16x16 fragment (row&15)

#define STAGE(buf, kt)                                                         \
  do {                                                                         \
    const unsigned short* Asrc = Ag + (kt) * 32;                               \
    const unsigned short* Bsrc = Bg + (kt) * 32;                               \
    _Pragma("unroll")                                                          \
    for (int it = 0; it < 2; ++it) {                                           \
      __builtin_amdgcn_global_load_lds(                                        \
          (const __attribute__((address_space(1))) void*)(Asrc + (size_t)it * 64 * 256), \
          (__attribute__((address_space(3))) void*)&lds[(buf) * 8192 + it * 2048 + wv * 512], \
          16, 0, 0);                                                           \
      __builtin_amdgcn_global_load_lds(                                        \
          (const __attribute__((address_space(1))) void*)(Bsrc + (size_t)it * 64 * 256), \
          (__attribute__((address_space(3))) void*)&lds[(buf) * 8192 + 4096 + it * 2048 + wv * 512], \
          16, 0, 0);                                                           \
    }                                                                          \
  } while (0)

// read swizzle: nominal gran = lane>>4, key = (row>>1)&3 = (lane>>1)&3
// (all fragment row bases are multiples of 16, row = base + (lane&15)).
#define COMPUTE(buf)                                                           \
  do {                                                                         \
    const int gsw = (((lane >> 4) ^ ((lane >> 1) & 3))) * 8;                   \
    bf16x8 af[4], bfr[4];                                                      \
    _Pragma("unroll")                                                          \
    for (int mi = 0; mi < 4; ++mi)                                             \
      af[mi] = *(const bf16x8*)&lds[(buf) * 8192 + (wr * 64 + mi * 16 + a_r) * 32 + gsw]; \
    _Pragma("unroll")                                                          \
    for (int ni = 0; ni < 4; ++ni)                                             \
      bfr[ni] = *(const bf16x8*)&lds[(buf) * 8192 + 4096 + (wc * 64 + ni * 16 + a_r) * 32 + gsw]; \
    _Pragma("unroll")                                                          \
    for (int mi = 0; mi < 4; ++mi)                                             \
      _Pragma("unroll")                                                        \
      for (int ni = 0; ni < 4; ++ni)                                           \
        acc[mi][ni] = __builtin_amdgcn_mfma_f32_16x16x32_bf16(                 \
            af[mi], bfr[ni], acc[mi][ni], 0, 0, 0);                            \
  } while (0)

  // Depth-2 prefetch, 4 loads/wave per STAGE; counted vmcnt, never 0 until
  // the final tile. 8 K-tiles rotate buffers 0,1,0,1,...
  STAGE(0, 0);
  STAGE(1, 1);
  WAITVM(4);  BARX();
  COMPUTE(0);  BARX();
  STAGE(0, 2); WAITVM(4); BARX();
  COMPUTE(1);  BARX();
  STAGE(1, 3); WAITVM(4); BARX();
  COMPUTE(0);  BARX();
  STAGE(0, 4); WAITVM(4); BARX();
  COMPUTE(1);  BARX();
  STAGE(1, 5); WAITVM(4); BARX();
  COMPUTE(0);  BARX();
  STAGE(0, 6); WAITVM(4); BARX();
  COMPUTE(1);  BARX();
  STAGE(1, 7); WAITVM(4); BARX();
  COMPUTE(0);  BARX();
  WAITVM(0);   BARX();
  COMPUTE(1);  BARX();   // LDS about to be reused by epilogue

  // ------------------- LDS-staged coalesced epilogue -------------------
  const int cl = wc * 64 + a_r;              // local col base
  const int rl = wr * 64 + (lane >> 4) * 4;  // local row base
  if (!OUTF32) {
    // 128 rows x (128+8) bf16 = 17408 ushorts (16B-aligned rows, bank spread)
    unsigned short* eb = &lds[0];
#pragma unroll
    for (int ni = 0; ni < 4; ++ni)
#pragma unroll
      for (int mi = 0; mi < 4; ++mi)
#pragma unroll
        for (int r = 0; r < 4; ++r)
          eb[(rl + mi * 16 + r) * 136 + cl + ni * 16] = f2bf(acc[mi][ni][r]);
    BARX();   // lgkmcnt(0) drain inside: publishes ds_writes to all waves
    unsigned short* C = (unsigned short*)Cout;
#pragma unroll
    for (int p = 0; p < 8; ++p) {
      const int idx = p * 256 + tid;
      const int row = idx >> 4;
      const int seg = idx & 15;
      uint4 v = *(const uint4*)&eb[row * 136 + seg * 8];
      *(uint4*)&C[(size_t)(m0 + row) * N + n0 + seg * 8] = v;
    }
  } else {
    // f32: two 64-row halves of (128+4)-f32-stride rows (33792 B each)
    float* ef = (float*)&lds[0];
    float* C = (float*)Cout;
    float bv[4];
#pragma unroll
    for (int ni = 0; ni < 4; ++ni) bv[ni] = bias[n0 + wc * 64 + ni * 16 + a_r];
#pragma unroll
    for (int half = 0; half < 2; ++half) {
      if (wr == half) {
        const int rb = (lane >> 4) * 4;   // local row within the half
#pragma unroll
        for (int ni = 0; ni < 4; ++ni)
#pragma unroll
          for (int mi = 0; mi < 4; ++mi)
#pragma unroll
            for (int r = 0; r < 4; ++r)
              ef[(rb + mi * 16 + r) * 132 + wc * 64 + ni * 16 + a_r] =
                  acc[mi][ni][r] + bv[ni];
      }
      BARX();   // lgkmcnt(0) drain inside
#pragma unroll
      for (int p = 0; p < 8; ++p) {
        const int idx = p * 256 + tid;
        const int row = idx >> 5;
        const int seg = idx & 31;
        f32x4 v = *(const f32x4*)&ef[row * 132 + seg * 4];
        *(f32x4*)&C[(size_t)(m0 + half * 64 + row) * N + n0 + seg * 4] = v;
      }
      BARX();
    }
  }
#undef STAGE
#undef COMPUTE
}

// --------------------------- dilated local attention -----------------------
// One block = 16x16 px tile x one combo, 512 threads: thread = (pixel, half),
// half = t&1 owns 16 channels (planes 2*half, 2*half+1). ONE 4-plane LDS
// buffer (31KB) reused K-then-V; OOB pixels zero-filled. Score = half-dot +
// one shfl_xor(1) per tap (lane pair shares a pixel). Softmax identical in
// both lanes. Layout [plane 0..3][485 px][16B]; tap (i,j) of pixel (ph,pw):
// lp = (ph+i*d)*22 + (pw+j*d); tile origin (h0-d, w0-d).
__global__ __launch_bounds__(512) void attn_kernel(
    const unsigned short* __restrict__ qkv, unsigned short* __restrict__ xo) {
  __shared__ __align__(16) unsigned short lds[4 * 485 * 8];   // 31040 B

  const int nwg = gridDim.x;            // 2048, %8 == 0
  const int q8  = nwg >> 3;
  const int nid = (blockIdx.x & 7) * q8 + (blockIdx.x >> 3);
  const int combo = nid & 7;
  const int tw    = (nid >> 3) & 7;
  const int th    = (nid >> 6) & 7;
  const int b     = nid >> 9;
  const int d     = (combo >> 2) ? 3 : 2;     // DILATIONS = (2, 3)
  const int choff = combo * 32;
  const int h0 = th * 16, w0 = tw * 16;
  const int t = threadIdx.x;

  // staging geometry (K and V): plane = t&3, px = it*128 + (t>>2), it<4.
  // it<3 always live; it==3 live iff t<400 (px<484). 4 consecutive lanes
  // fetch one contiguous 64B global segment.
  const int splane = t & 3;
  const int t4     = t >> 2;
  const int schoff = choff + splane * 8;

  // ---- stage K (zero-filled OOB) ----
#pragma unroll
  for (int it = 0; it < 4; ++it) {
    const int px = it * 128 + t4;
    const int r = px / 22, c = px % 22;     // magic-mul
    const int gh = h0 - d + r;
    const int gw = w0 - d + c;
    const bool ok = ((unsigned)gh < 128u) && ((unsigned)gw < 128u);
    const int hcl = min(max(gh, 0), 127);
    const int wcl = min(max(gw, 0), 127);
    const int gp = (((b << 7) | hcl) << 7) | wcl;
    uint4 u = *(const uint4*)(qkv + (size_t)gp * 768 + 256 + schoff);
    if (!ok) u = make_uint4(0u, 0u, 0u, 0u);
    if (it < 3 || t < 400) *(uint4*)&lds[(splane * 485 + px) * 8] = u;
  }

  // ---- q (16 ch for this half), scale folded in ----
  const int half = t & 1;
  const int ph = (t >> 1) >> 4, pw = (t >> 1) & 15;
  const int gp0 = (((b << 7) | (h0 + ph)) << 7) | (w0 + pw);
  const unsigned short* qp = qkv + (size_t)gp0 * 768 + choff + half * 16;
  uint4 uq0 = *(const uint4*)qp;
  uint4 uq1 = *(const uint4*)(qp + 8);
  f32x2 q2[8];
  {
    const f32x2 s2 = {0.17677669529663687f, 0.17677669529663687f};  // 32^-0.5
    q2[0] = up2(uq0.x) * s2; q2[1] = up2(uq0.y) * s2;
    q2[2] = up2(uq0.z) * s2; q2[3] = up2(uq0.w) * s2;
    q2[4] = up2(uq1.x) * s2; q2[5] = up2(uq1.y) * s2;
    q2[6] = up2(uq1.z) * s2; q2[7] = up2(uq1.w) * s2;
  }
  __syncthreads();

  // ---- scores: 9 taps, 2 planes each (this half), branch-free ----
  const int p0 = 2 * half, p1 = 2 * half + 1;
  float sc[9];
#pragma unroll
  for (int i = 0; i < 3; ++i) {
#pragma unroll
    for (int j = 0; j < 3; ++j) {
      const int lp = (ph + i * d) * 22 + (pw + j * d);
      const uint4 k0 = *(const uint4*)&lds[(p0 * 485 + lp) * 8];
      const uint4 k1 = *(const uint4*)&lds[(p1 * 485 + lp) * 8];
      f32x2 a = q2[0] * up2(k0.x);
      a += q2[1] * up2(k0.y); a += q2[2] * up2(k0.z); a += q2[3] * up2(k0.w);
      a += q2[4] * up2(k1.x); a += q2[5] * up2(k1.y);
      a += q2[6] * up2(k1.z); a += q2[7] * up2(k1.w);
      sc[i * 3 + j] = a.x + a.y;        // half-dot
    }
  }
  // complete the 32-ch dot across the lane pair
#pragma unroll
  for (int k = 0; k < 9; ++k) sc[k] += __shfl_xor(sc[k], 1);

  // ---- softmax over 9 (identical in both halves) ----
  float mx = sc[0];
#pragma unroll
  for (int k = 1; k < 9; ++k) mx = fmaxf(mx, sc[k]);
  float sum = 0.f;
#pragma unroll
  for (int k = 0; k < 9; ++k) { sc[k] = __expf(sc[k] - mx); sum += sc[k]; }
  const float inv = 1.f / sum;

  // ---- all waves done reading K; overwrite buffer with V ----
  __syncthreads();
#pragma unroll
  for (int it = 0; it < 4; ++it) {
    const int px = it * 128 + t4;
    const int r = px / 22, c = px % 22;
    const int gh = h0 - d + r;
    const int gw = w0 - d + c;
    const bool ok = ((unsigned)gh < 128u) && ((unsigned)gw < 128u);
    const int hcl = min(max(gh, 0), 127);
    const int wcl = min(max(gw, 0), 127);
    const int gp = (((b << 7) | hcl) << 7) | wcl;
    uint4 u = *(const uint4*)(qkv + (size_t)gp * 768 + 512 + schoff);
    if (!ok) u = make_uint4(0u, 0u, 0u, 0u);
    if (it < 3 || t < 400) *(uint4*)&lds[(splane * 485 + px) * 8] = u;
  }
  __syncthreads();

  // ---- weighted V accumulate (this half's 16 ch), branch-free ----
  f32x2 o2[8];
#pragma unroll
  for (int k = 0; k < 8; ++k) o2[k] = (f32x2){0.f, 0.f};
#pragma unroll
  for (int i = 0; i < 3; ++i) {
#pragma unroll
    for (int j = 0; j < 3; ++j) {
      const int lp = (ph + i * d) * 22 + (pw + j * d);
      const uint4 v0 = *(const uint4*)&lds[(p0 * 485 + lp) * 8];
      const uint4 v1 = *(const uint4*)&lds[(p1 * 485 + lp) * 8];
      const float wv = sc[i * 3 + j] * inv;
      const f32x2 w2 = {wv, wv};
      o2[0] += w2 * up2(v0.x); o2[1] += w2 * up2(v0.y);
      o2[2] += w2 * up2(v0.z); o2[3] += w2 * up2(v0.w);
      o2[4] += w2 * up2(v1.x); o2[5] += w2 * up2(v1.y);
      o2[6] += w2 * up2(v1.z); o2[7] += w2 * up2(v1.w);
    }
  }

  // ---- store 16 ch bf16 ----
  unsigned short* op = xo + (size_t)gp0 * 256 + choff + half * 16;
  uint4 s0, s1;
  s0.x = pk2bf(o2[0].x, o2[0].y); s0.y = pk2bf(o2[1].x, o2[1].y);
  s0.z = pk2bf(o2[2].x, o2[2].y); s0.w = pk2bf(o2[3].x, o2[3].y);
  s1.x = pk2bf(o2[4].x, o2[4].y); s1.y = pk2bf(o2[5].x, o2[5].y);
  s1.z = pk2bf(o2[6].x, o2[6].y); s1.w = pk2bf(o2[7].x, o2[7].y);
  *(uint4*)op       = s0;
  *(uint4*)(op + 8) = s1;
}

// ---------------------------------------------------------------------------
extern "C" void kernel_launch(void* const* d_in, const int* in_sizes, int n_in,
                              void* d_out, int out_size, void* d_ws, size_t ws_size,
                              hipStream_t stream) {
  const float* x     = (const float*)d_in[0];
  const float* Wqkv  = (const float*)d_in[1];
  const float* Wproj = (const float*)d_in[2];
  const float* bproj = (const float*)d_in[3];

  const int M = 4 * 128 * 128;   // 65536 pixels
  const int C = 256;

  // workspace layout (bf16 ushorts): xb | qkv | xo | Wqkv_b | Wproj_b  (~161 MB)
  unsigned short* xb     = (unsigned short*)d_ws;
  unsigned short* qkvb   = xb + (size_t)M * C;
  unsigned short* xob    = qkvb + (size_t)M * 3 * C;
  unsigned short* wqkvb  = xob + (size_t)M * C;
  unsigned short* wprojb = wqkvb + (size_t)3 * C * C;

  cvt_f32_to_bf16<<<(M * C / 8 + 255) / 256, 256, 0, stream>>>(x, xb, M * C);
  // both weight matrices: (3*C*C + C*C)/8 / 256 = 128 blocks, dsts contiguous
  cvt_w_both<<<128, 256, 0, stream>>>(Wqkv, Wproj, wqkvb);

  gemm_bt<0><<<(M / 128) * (3 * C / 128), 256, 0, stream>>>(
      xb, wqkvb, (void*)qkvb, nullptr, 3 * C, 3 * C / 128);

  // 4 batches x 8x8 tiles x 8 combos = 2048 blocks, 512 threads (px x half)
  attn_kernel<<<2048, 512, 0, stream>>>(qkvb, xob);

  gemm_bt<1><<<(M / 128) * (C / 128), 256, 0, stream>>>(
      xob, wprojb, d_out, bproj, C, C / 128);
}